// Round 1
// baseline (525.906 us; speedup 1.0000x reference)
//
#include <hip/hip_runtime.h>
#include <hip/hip_bf16.h>

typedef __bf16 bf16x8 __attribute__((ext_vector_type(8)));
typedef float  f32x4  __attribute__((ext_vector_type(4)));

#define HD  128   // hidden dim
#define ROW 256   // 2*HD floats per row

// One block: 256 threads = 4 waves. Each chunk = 64 rows (16 rows per wave).
// W (128x128) is bf16-converted and pre-swizzled into LDS in MFMA B-fragment
// order once per block; K-loop is ds_read_b128 + v_mfma_f32_16x16x32_bf16.
__global__ __launch_bounds__(256, 4)
void revnet_mfma(const float* __restrict__ x, const float* __restrict__ w,
                 float* __restrict__ out, int num_chunks) {
    // 8 n-tiles * 4 k-steps * 64 lanes * 8 bf16 = 16384 bf16 = 32 KB
    __shared__ __attribute__((aligned(16))) __bf16 ldsB[2048 * 8];

    const int tid    = threadIdx.x;
    const int lane   = tid & 63;
    const int wave   = tid >> 6;
    const int lane15 = lane & 15;
    const int quad   = lane >> 4;

    // ---- fill W fragments into LDS (B-operand layout for 16x16x32 bf16) ----
    // slot s = (nt*4 + ks)*64 + lane ; each slot holds B[k0+j][n], j=0..7
    #pragma unroll
    for (int i = 0; i < 8; ++i) {
        int s  = i * 256 + tid;
        int sl = s & 63;
        int t  = s >> 6;
        int ks = t & 3;
        int nt = t >> 2;
        int k0 = ks * 32 + (sl >> 4) * 8;
        int n  = nt * 16 + (sl & 15);
        bf16x8 frag;
        #pragma unroll
        for (int j = 0; j < 8; ++j)
            frag[j] = (__bf16)w[(k0 + j) * HD + n];
        *(bf16x8*)&ldsB[s * 8] = frag;
    }
    __syncthreads();

    for (int c = blockIdx.x; c < num_chunks; c += gridDim.x) {
        const int m0   = c * 64 + wave * 16;
        const int arow = m0 + lane15;
        const float* __restrict__ xr = x   + (size_t)arow * ROW;
        float*       __restrict__ yr = out + (size_t)arow * ROW;

        // A fragments: lane holds A[m=lane15][k = ks*32 + quad*8 + j]
        // (8 contiguous floats -> two dwordx4 loads; also the x1 passthrough)
        bf16x8 afrag[4];
        #pragma unroll
        for (int ks = 0; ks < 4; ++ks) {
            const int k0 = ks * 32 + quad * 8;
            f32x4 v0 = *(const f32x4*)(xr + k0);
            f32x4 v1 = *(const f32x4*)(xr + k0 + 4);
            *(f32x4*)(yr + k0)     = v0;   // out[:, :128] = x1 (exact fp32)
            *(f32x4*)(yr + k0 + 4) = v1;
            #pragma unroll
            for (int j = 0; j < 4; ++j) {
                afrag[ks][j]     = (__bf16)v0[j];
                afrag[ks][j + 4] = (__bf16)v1[j];
            }
        }

        f32x4 acc[8];
        #pragma unroll
        for (int nt = 0; nt < 8; ++nt) acc[nt] = (f32x4){0.f, 0.f, 0.f, 0.f};

        #pragma unroll
        for (int ks = 0; ks < 4; ++ks) {
            #pragma unroll
            for (int nt = 0; nt < 8; ++nt) {
                bf16x8 bfrag = *(const bf16x8*)&ldsB[((nt * 4 + ks) * 64 + lane) * 8];
                acc[nt] = __builtin_amdgcn_mfma_f32_16x16x32_bf16(
                              afrag[ks], bfrag, acc[nt], 0, 0, 0);
            }
        }

        // ---- epilogue: y2 = x2 + h ----
        // C/D layout: col = lane15, row = quad*4 + r  (m89-verified)
        #pragma unroll
        for (int nt = 0; nt < 8; ++nt) {
            const int col = HD + nt * 16 + lane15;
            #pragma unroll
            for (int r = 0; r < 4; ++r) {
                const size_t idx = (size_t)(m0 + quad * 4 + r) * ROW + col;
                out[idx] = x[idx] + acc[nt][r];
            }
        }
    }
}

extern "C" void kernel_launch(void* const* d_in, const int* in_sizes, int n_in,
                              void* d_out, int out_size, void* d_ws, size_t ws_size,
                              hipStream_t stream) {
    const float* x   = (const float*)d_in[0];
    const float* w   = (const float*)d_in[1];
    float*       out = (float*)d_out;

    const int rows       = out_size / ROW;   // 262144
    const int num_chunks = rows / 64;        // 4096
    int grid = num_chunks < 1024 ? num_chunks : 1024;

    revnet_mfma<<<dim3(grid), dim3(256), 0, stream>>>(x, w, out, num_chunks);
}